// Round 1
// baseline (781.270 us; speedup 1.0000x reference)
//
#include <hip/hip_runtime.h>
#include <math.h>

// ---------------------------------------------------------------------------
// Dual CTC loss forward (PyTorch semantics: blank=0, mean reduction,
// zero_infinity), matching the JAX reference.
//  error task:   B=32, T=2000, C=4,  S=50,  L=101
//  phoneme task: B=32, T=2000, C=64, S=200, L=401
// Strategy:
//  1) parallel kernel: per-(b,t) log-softmax denominator in log2 units
//  2) serial kernel: one wave per (task,b) chain; alpha in registers,
//     cross-lane deps via __shfl_up, no barriers in the T loop.
// ---------------------------------------------------------------------------

#define NEGV -1e30f
static constexpr float LOG2E = 1.4426950408889634f;   // 1/ln(2)
static constexpr float LN2F  = 0.6931471805599453f;

__device__ __forceinline__ float fexp2(float x) {
#if __has_builtin(__builtin_amdgcn_exp2f)
  return __builtin_amdgcn_exp2f(x);   // v_exp_f32: 2^x
#else
  return exp2f(x);
#endif
}
__device__ __forceinline__ float flog2(float x) {
#if __has_builtin(__builtin_amdgcn_logf)
  return __builtin_amdgcn_logf(x);    // v_log_f32: log2(x)
#else
  return log2f(x);
#endif
}

// lse2[r] = log2( sum_c 2^(x[r,c] * LOG2E) )  == ln-logsumexp * LOG2E
template <int C>
__global__ __launch_bounds__(256) void lse_rows_kernel(
    const float* __restrict__ x, float* __restrict__ out, int nrows) {
  int r = blockIdx.x * blockDim.x + threadIdx.x;
  if (r >= nrows) return;
  const float* row = x + (size_t)r * C;
  float z[C];
#pragma unroll
  for (int i = 0; i < C; i += 4) {
    const float4 v = *reinterpret_cast<const float4*>(row + i);
    z[i]     = v.x * LOG2E;
    z[i + 1] = v.y * LOG2E;
    z[i + 2] = v.z * LOG2E;
    z[i + 3] = v.w * LOG2E;
  }
  float m = z[0];
#pragma unroll
  for (int i = 1; i < C; ++i) m = fmaxf(m, z[i]);
  float s = 0.f;
#pragma unroll
  for (int i = 0; i < C; ++i) s += fexp2(z[i] - m);
  out[r] = m + flog2(s);
}

// One wave (64 lanes) advances one CTC chain. Lane i holds extended-label
// positions l = i*R .. i*R+R-1 in registers (log2-domain alpha).
template <int C, int S, int R>
__device__ __forceinline__ void ctc_chain(
    const float* __restrict__ logits_b,  // [T, C] for this b
    const int* __restrict__ tgt_b,       // [S]
    const float* __restrict__ lse_b,     // [T] (log2 units)
    int len, int tl, float* __restrict__ out, float* sa /* >= 64*R floats */) {
  constexpr int L = 2 * S + 1;
  const int lane = threadIdx.x;

  // ext (class per extended position) and can_skip, fixed for the whole chain
  int ext[R];
  bool skip[R];
#pragma unroll
  for (int j = 0; j < R; ++j) {
    const int l = lane * R + j;
    int cls = 0;
    bool sk = false;
    if (l & 1) {
      const int s = (l - 1) >> 1;
      const int sc = (s < S) ? s : (S - 1);  // clamp for dummy l >= L
      cls = tgt_b[sc];
      if (s >= 1 && s < S) sk = (cls != tgt_b[s - 1]);
    }
    ext[j] = cls;
    skip[j] = sk;
  }

  // t = 0 init: alpha[0] = lp(blank), alpha[1] = lp(first label), rest NEG
  float alpha[R];
  {
    const float lse0 = lse_b[0];
#pragma unroll
    for (int j = 0; j < R; ++j) {
      const int l = lane * R + j;
      alpha[j] = (l <= 1) ? fmaf(logits_b[ext[j]], LOG2E, -lse0) : NEGV;
    }
  }

  // software pipeline: prefetch next step's gathered logits + lse
  float lpn[R], lsen;
  {
    const int tp = (len > 1) ? 1 : 0;
    const float* row = logits_b + (size_t)tp * C;
#pragma unroll
    for (int j = 0; j < R; ++j) lpn[j] = row[ext[j]];
    lsen = lse_b[tp];
  }

  for (int t = 1; t < len; ++t) {
    float lpc[R];
#pragma unroll
    for (int j = 0; j < R; ++j) lpc[j] = lpn[j];
    const float lsc = lsen;
    const int tp = (t + 1 < len) ? (t + 1) : t;
    const float* row = logits_b + (size_t)tp * C;
#pragma unroll
    for (int j = 0; j < R; ++j) lpn[j] = row[ext[j]];
    lsen = lse_b[tp];

    // previous lane's top-two alpha values (l-1, l-2 across lane boundary)
    float am1 = __shfl_up(alpha[R - 1], 1, 64);
    float am2 = __shfl_up(alpha[R - 2], 1, 64);
    if (lane == 0) { am1 = NEGV; am2 = NEGV; }

    float na[R];
#pragma unroll
    for (int j = 0; j < R; ++j) {
      const float a0 = alpha[j];
      const float a1 = (j >= 1) ? alpha[j - 1] : am1;
      float a2 = (j >= 2) ? alpha[j - 2] : ((j == 1) ? am1 : am2);
      a2 = skip[j] ? a2 : NEGV;
      const float m = fmaxf(a0, fmaxf(a1, a2));
      const float ssum = fexp2(a0 - m) + fexp2(a1 - m) + fexp2(a2 - m);
      na[j] = fmaf(lpc[j], LOG2E, m - lsc) + flog2(ssum);
    }
#pragma unroll
    for (int j = 0; j < R; ++j) alpha[j] = na[j];
  }

  // readout: alpha[2*tl-1], alpha[2*tl] via LDS
#pragma unroll
  for (int j = 0; j < R; ++j) {
    const int l = lane * R + j;
    if (l < L) sa[l] = alpha[j];
  }
  __syncthreads();
  if (lane == 0) {
    const float a = sa[2 * tl - 1];
    const float b = sa[2 * tl];
    const float m = fmaxf(a, b);
    float loss = -LN2F * (m + flog2(fexp2(a - m) + fexp2(b - m)));
    if (loss > 1e29f) loss = 0.f;  // zero_infinity
    atomicAdd(out, loss / ((float)tl * 32.0f));
  }
}

__global__ __launch_bounds__(64) void ctc_chains_kernel(
    const float* __restrict__ err_logits, const float* __restrict__ ph_logits,
    const int* __restrict__ err_tgt, const int* __restrict__ ph_tgt,
    const int* __restrict__ err_il, const int* __restrict__ ph_il,
    const int* __restrict__ err_tl, const int* __restrict__ ph_tl,
    const float* __restrict__ lse_err, const float* __restrict__ lse_ph,
    float* __restrict__ out) {
  __shared__ float sa[64 * 7];
  const int T = 2000;
  const int blk = blockIdx.x;
  if (blk < 32) {
    const int b = blk;
    int len = err_il[b];
    if (len > T) len = T;
    ctc_chain<4, 50, 2>(err_logits + (size_t)b * T * 4, err_tgt + b * 50,
                        lse_err + (size_t)b * T, len, err_tl[b], out, sa);
  } else {
    const int b = blk - 32;
    int len = ph_il[b];
    if (len > T) len = T;
    ctc_chain<64, 200, 7>(ph_logits + (size_t)b * T * 64, ph_tgt + b * 200,
                          lse_ph + (size_t)b * T, len, ph_tl[b], out, sa);
  }
}

extern "C" void kernel_launch(void* const* d_in, const int* in_sizes, int n_in,
                              void* d_out, int out_size, void* d_ws,
                              size_t ws_size, hipStream_t stream) {
  const float* err_logits = (const float*)d_in[0];
  const float* ph_logits  = (const float*)d_in[1];
  const int* err_tgt = (const int*)d_in[2];
  const int* ph_tgt  = (const int*)d_in[3];
  const int* err_il  = (const int*)d_in[4];
  const int* ph_il   = (const int*)d_in[5];
  const int* err_tl  = (const int*)d_in[6];
  const int* ph_tl   = (const int*)d_in[7];
  float* out = (float*)d_out;

  const int B = 32, T = 2000;
  const int rows = B * T;
  float* lse_err = (float*)d_ws;            // rows floats
  float* lse_ph  = lse_err + rows;          // rows floats (total 512 KB of ws)

  hipMemsetAsync(d_out, 0, sizeof(float), stream);
  lse_rows_kernel<4><<<(rows + 255) / 256, 256, 0, stream>>>(err_logits, lse_err, rows);
  lse_rows_kernel<64><<<(rows + 255) / 256, 256, 0, stream>>>(ph_logits, lse_ph, rows);
  ctc_chains_kernel<<<64, 64, 0, stream>>>(err_logits, ph_logits, err_tgt,
                                           ph_tgt, err_il, ph_il, err_tl,
                                           ph_tl, lse_err, lse_ph, out);
}

// Round 2
// 652.547 us; speedup vs baseline: 1.1973x; 1.1973x over previous
//
#include <hip/hip_runtime.h>
#include <math.h>

// ---------------------------------------------------------------------------
// Dual CTC loss forward, linear-probability-domain fp64 recursion.
//  error task:   B=32, T=2000, C=4,  S=50,  L=101  (R=2 positions/lane)
//  phoneme task: B=32, T=2000, C=64, S=200, L=401  (R=7 positions/lane)
// Kernel 1/2: parallel softmax probs p[b,t,c] (fp32).
// Kernel 3: one wave per chain; alpha in fp64 registers; per-step update
//   a' = p * (a0 + a1 + skip*a2)  -- no transcendentals in the T loop.
//   Power-of-2 renorm every 32 steps via exponent-field extraction.
//   Row load: 1 coalesced dword/lane/step + 7 ds_bpermute class gathers.
// ---------------------------------------------------------------------------

static constexpr float  LOG2E = 1.4426950408889634f;
static constexpr double LN2D  = 0.6931471805599453;

__device__ __forceinline__ float fexp2(float x) {
  return __builtin_amdgcn_exp2f(x);
}

// error softmax: one thread per row (C=4)
__global__ __launch_bounds__(256) void softmax4_kernel(
    const float* __restrict__ x, float* __restrict__ p, int nrows) {
  int r = blockIdx.x * blockDim.x + threadIdx.x;
  if (r >= nrows) return;
  float4 v = *reinterpret_cast<const float4*>(x + (size_t)r * 4);
  float z0 = v.x * LOG2E, z1 = v.y * LOG2E, z2 = v.z * LOG2E, z3 = v.w * LOG2E;
  float m = fmaxf(fmaxf(z0, z1), fmaxf(z2, z3));
  float e0 = fexp2(z0 - m), e1 = fexp2(z1 - m);
  float e2 = fexp2(z2 - m), e3 = fexp2(z3 - m);
  float inv = 1.0f / (e0 + e1 + e2 + e3);
  float4 o;
  o.x = e0 * inv; o.y = e1 * inv; o.z = e2 * inv; o.w = e3 * inv;
  *reinterpret_cast<float4*>(p + (size_t)r * 4) = o;
}

// phoneme softmax: one wave per row (C=64)
__global__ __launch_bounds__(256) void softmax64_kernel(
    const float* __restrict__ x, float* __restrict__ p, int nrows) {
  int row = blockIdx.x * 4 + (threadIdx.x >> 6);
  int lane = threadIdx.x & 63;
  if (row >= nrows) return;
  float z = x[(size_t)row * 64 + lane] * LOG2E;
  float m = z;
#pragma unroll
  for (int off = 32; off >= 1; off >>= 1) m = fmaxf(m, __shfl_xor(m, off, 64));
  float e = fexp2(z - m);
  float s = e;
#pragma unroll
  for (int off = 32; off >= 1; off >>= 1) s += __shfl_xor(s, off, 64);
  p[(size_t)row * 64 + lane] = e * (1.0f / s);
}

// One wave advances one chain. Lane i holds extended positions
// l = i*R .. i*R+R-1; alpha in fp64, linear domain, stored = true * 2^K.
template <int C, int S, int R>
__device__ __forceinline__ void ctc_chain_lin(
    const float* __restrict__ p_b,   // [T, C] softmax probs for this b
    const int* __restrict__ tgt_b,   // [S]
    int len, int tl, float* __restrict__ out, double* sa) {
  constexpr int L = 2 * S + 1;
  const int lane = threadIdx.x;

  int idx[R];        // byte index for ds_bpermute (= class * 4)
  double skipm[R];   // 1.0 if l can take the l-2 skip transition
#pragma unroll
  for (int j = 0; j < R; ++j) {
    const int l = lane * R + j;
    int cls = 0;
    bool sk = false;
    if (l & 1) {
      const int s = (l - 1) >> 1;
      const int sc = (s < S) ? s : (S - 1);  // clamp for dummy l >= L
      cls = tgt_b[sc];
      if (s >= 1 && s < S) sk = (cls != tgt_b[s - 1]);
    }
    idx[j] = cls * 4;
    skipm[j] = sk ? 1.0 : 0.0;
  }

  // t = 0 init: alpha[0] = p(blank), alpha[1] = p(first label), rest 0
  double alpha[R];
#pragma unroll
  for (int j = 0; j < R; ++j) {
    const int l = lane * R + j;
    alpha[j] = (l <= 1) ? (double)p_b[idx[j] >> 2] : 0.0;
  }
  int K = 0;  // stored = true * 2^K

  const int cl = lane & (C - 1);
  // software pipeline: rv holds row t+1's coalesced values; pf holds
  // this step's bpermuted (per-position) probs.
  float rv = p_b[(size_t)((1 < len - 1) ? 1 : (len - 1)) * C + cl];
  float pf[R];
#pragma unroll
  for (int j = 0; j < R; ++j)
    pf[j] = __int_as_float(__builtin_amdgcn_ds_bpermute(idx[j], __float_as_int(rv)));
  rv = p_b[(size_t)((2 < len - 1) ? 2 : (len - 1)) * C + cl];

  for (int t = 1; t < len; ++t) {
    // periodic power-of-2 renorm (wave-uniform branch)
    if ((t & 31) == 0) {
      double m = alpha[0];
#pragma unroll
      for (int j = 1; j < R; ++j) m = fmax(m, alpha[j]);
#pragma unroll
      for (int off = 1; off < 64; off <<= 1) m = fmax(m, __shfl_xor(m, off, 64));
      const long long bits = __double_as_longlong(m);
      const int e = (int)((bits >> 52) & 0x7FF);
      if (e > 0) {
        const double sc = __longlong_as_double((long long)(2046 - e) << 52);
#pragma unroll
        for (int j = 0; j < R; ++j) alpha[j] *= sc;
        K += 1023 - e;
      }
    }

    // issue coalesced load for row t+2
    const int tn = (t + 2 < len) ? (t + 2) : (len - 1);
    const float rvn = p_b[(size_t)tn * C + cl];

    // bpermute row t+1 while computing step t (DS latency overlaps f64 math)
    float pfn[R];
#pragma unroll
    for (int j = 0; j < R; ++j)
      pfn[j] = __int_as_float(__builtin_amdgcn_ds_bpermute(idx[j], __float_as_int(rv)));

    // cross-lane neighbors (prev lane's top two positions)
    double am1 = __shfl_up(alpha[R - 1], 1, 64);
    double am2 = __shfl_up(alpha[R - 2], 1, 64);
    if (lane == 0) { am1 = 0.0; am2 = 0.0; }

    double na[R];
#pragma unroll
    for (int j = 0; j < R; ++j) {
      const double a0 = alpha[j];
      const double a1 = (j >= 1) ? alpha[j - 1] : am1;
      const double a2 = (j >= 2) ? alpha[j - 2] : ((j == 1) ? am1 : am2);
      double s = a0 + a1;
      s = fma(skipm[j], a2, s);
      na[j] = (double)pf[j] * s;
    }
#pragma unroll
    for (int j = 0; j < R; ++j) alpha[j] = na[j];
#pragma unroll
    for (int j = 0; j < R; ++j) pf[j] = pfn[j];
    rv = rvn;
  }

  // readout alpha[2tl-1] + alpha[2tl] via LDS
#pragma unroll
  for (int j = 0; j < R; ++j) {
    const int l = lane * R + j;
    if (l < L) sa[l] = alpha[j];
  }
  __syncthreads();
  if (lane == 0) {
    const double a = sa[2 * tl - 1] + sa[2 * tl];
    // true loss = -(ln stored - K ln2) = K ln2 - ln stored
    float loss = (float)((double)K * LN2D - log(a));
    if (!(loss < 1e29f)) loss = 0.0f;  // zero_infinity (a==0 -> +inf -> 0)
    atomicAdd(out, loss / ((float)tl * 32.0f));
  }
}

__global__ __launch_bounds__(64) void ctc_chains_kernel(
    const float* __restrict__ p_err, const float* __restrict__ p_ph,
    const int* __restrict__ err_tgt, const int* __restrict__ ph_tgt,
    const int* __restrict__ err_il, const int* __restrict__ ph_il,
    const int* __restrict__ err_tl, const int* __restrict__ ph_tl,
    float* __restrict__ out) {
  __shared__ double sa[512];
  const int T = 2000;
  const int blk = blockIdx.x;
  if (blk < 32) {
    const int b = blk;
    int len = err_il[b];
    if (len > T) len = T;
    ctc_chain_lin<4, 50, 2>(p_err + (size_t)b * T * 4, err_tgt + b * 50, len,
                            err_tl[b], out, sa);
  } else {
    const int b = blk - 32;
    int len = ph_il[b];
    if (len > T) len = T;
    ctc_chain_lin<64, 200, 7>(p_ph + (size_t)b * T * 64, ph_tgt + b * 200, len,
                              ph_tl[b], out, sa);
  }
}

extern "C" void kernel_launch(void* const* d_in, const int* in_sizes, int n_in,
                              void* d_out, int out_size, void* d_ws,
                              size_t ws_size, hipStream_t stream) {
  const float* err_logits = (const float*)d_in[0];
  const float* ph_logits  = (const float*)d_in[1];
  const int* err_tgt = (const int*)d_in[2];
  const int* ph_tgt  = (const int*)d_in[3];
  const int* err_il  = (const int*)d_in[4];
  const int* ph_il   = (const int*)d_in[5];
  const int* err_tl  = (const int*)d_in[6];
  const int* ph_tl   = (const int*)d_in[7];
  float* out = (float*)d_out;

  const int B = 32, T = 2000;
  const int rows = B * T;
  float* p_err = (float*)d_ws;                 // rows*4 floats (1 MB)
  float* p_ph  = p_err + (size_t)rows * 4;     // rows*64 floats (16.4 MB)

  hipMemsetAsync(d_out, 0, sizeof(float), stream);
  softmax4_kernel<<<(rows + 255) / 256, 256, 0, stream>>>(err_logits, p_err, rows);
  softmax64_kernel<<<(rows + 3) / 4, 256, 0, stream>>>(ph_logits, p_ph, rows);
  ctc_chains_kernel<<<64, 64, 0, stream>>>(p_err, p_ph, err_tgt, ph_tgt,
                                           err_il, ph_il, err_tl, ph_tl, out);
}

// Round 4
// 306.973 us; speedup vs baseline: 2.5451x; 2.1258x over previous
//
#include <hip/hip_runtime.h>
#include <math.h>

// ---------------------------------------------------------------------------
// Dual CTC loss forward, linear-probability fp64 recursion.
//  error task:   B=32, T=2000, C=4,  S=50,  L=101  (R=2 positions/lane)
//  phoneme task: B=32, T=2000, C=64, S=200, L=401  (R=7 positions/lane)
// R4: R3 structure with fixed renormalization.
//  - gather kernels pre-expand softmax probs to G[chain][t][lane][RF]
//  - chain kernel: 2 coalesced vector loads/step, 8-deep register ring
//    prefetch; cross-lane alpha via DPP wave_shr:1 (VALU, no lgkmcnt)
//  - renorm every 16 steps, band max pinned to ~2^500 (not 2^0): fixes the
//    differential-underflow flush of the lagging (readout-feeding) band
//    that broke R3 at cadence 64 / target 2^0.
// Falls back to the R2 (bpermute) proven path if ws_size < ~165 MB.
// ---------------------------------------------------------------------------

static constexpr float  LOG2E = 1.4426950408889634f;
static constexpr double LN2D  = 0.6931471805599453;

#define DPP_WAVE_SHR1   0x138
#define DPP_ROW_SHR(n)  (0x110 | (n))
#define DPP_ROW_BCAST15 0x142
#define DPP_ROW_BCAST31 0x143

__device__ __forceinline__ float fexp2(float x) {
  return __builtin_amdgcn_exp2f(x);
}

// prev-lane value (lane i gets lane i-1; lane 0 gets 0.0) — pure VALU
__device__ __forceinline__ double dpp_shr1_f64(double x) {
  int lo = __double2loint(x), hi = __double2hiint(x);
  lo = __builtin_amdgcn_update_dpp(0, lo, DPP_WAVE_SHR1, 0xf, 0xf, true);
  hi = __builtin_amdgcn_update_dpp(0, hi, DPP_WAVE_SHR1, 0xf, 0xf, true);
  return __hiloint2double(hi, lo);
}

__device__ __forceinline__ int imax2(int a, int b) { return a > b ? a : b; }

// wave-wide int max (values >= 0) via DPP reduction, result as scalar
__device__ __forceinline__ int wave_imax(int v) {
  v = imax2(v, __builtin_amdgcn_update_dpp(0, v, DPP_ROW_SHR(1), 0xf, 0xf, true));
  v = imax2(v, __builtin_amdgcn_update_dpp(0, v, DPP_ROW_SHR(2), 0xf, 0xf, true));
  v = imax2(v, __builtin_amdgcn_update_dpp(0, v, DPP_ROW_SHR(4), 0xf, 0xf, true));
  v = imax2(v, __builtin_amdgcn_update_dpp(0, v, DPP_ROW_SHR(8), 0xf, 0xf, true));
  v = imax2(v, __builtin_amdgcn_update_dpp(0, v, DPP_ROW_BCAST15, 0xf, 0xf, true));
  v = imax2(v, __builtin_amdgcn_update_dpp(0, v, DPP_ROW_BCAST31, 0xf, 0xf, true));
  return __builtin_amdgcn_readlane(v, 63);
}

// ========================= fast path =======================================

// phoneme gather: softmax over C=64 (one wave/row) + bpermute expansion
__global__ __launch_bounds__(256) void gather_ph_kernel(
    const float* __restrict__ logits, const int* __restrict__ tgt,
    float* __restrict__ G) {
  const int lane = threadIdx.x & 63;
  const int t = blockIdx.x * 4 + (threadIdx.x >> 6);
  const int b = blockIdx.y;
  const float z = logits[((size_t)b * 2000 + t) * 64 + lane] * LOG2E;
  float m = z;
#pragma unroll
  for (int off = 32; off >= 1; off >>= 1) m = fmaxf(m, __shfl_xor(m, off, 64));
  const float e = fexp2(z - m);
  float s = e;
#pragma unroll
  for (int off = 32; off >= 1; off >>= 1) s += __shfl_xor(s, off, 64);
  const int pi = __float_as_int(e * (1.0f / s));
  const int* tb = tgt + b * 200;
  float o[8];
#pragma unroll
  for (int j = 0; j < 7; ++j) {
    const int l = lane * 7 + j;
    int cls = 0;
    if (l & 1) {
      const int ss = (l - 1) >> 1;
      cls = tb[ss < 200 ? ss : 199];
    }
    o[j] = __int_as_float(__builtin_amdgcn_ds_bpermute(cls << 2, pi));
  }
  o[7] = 0.f;
  float* dst = G + ((size_t)b * 2008 + t) * 512 + lane * 8;
  *(float4*)dst = make_float4(o[0], o[1], o[2], o[3]);
  *(float4*)(dst + 4) = make_float4(o[4], o[5], o[6], o[7]);
}

// error gather: per-row softmax over C=4 (redundant per lane, cheap)
__global__ __launch_bounds__(256) void gather_err_kernel(
    const float* __restrict__ logits, const int* __restrict__ tgt,
    float* __restrict__ G) {
  const int lane = threadIdx.x & 63;
  const int t = blockIdx.x * 4 + (threadIdx.x >> 6);
  const int b = blockIdx.y;
  const float4 v = *(const float4*)(logits + ((size_t)b * 2000 + t) * 4);
  const float z0 = v.x * LOG2E, z1 = v.y * LOG2E, z2 = v.z * LOG2E, z3 = v.w * LOG2E;
  const float m = fmaxf(fmaxf(z0, z1), fmaxf(z2, z3));
  const float e0 = fexp2(z0 - m), e1 = fexp2(z1 - m);
  const float e2 = fexp2(z2 - m), e3 = fexp2(z3 - m);
  const float inv = 1.0f / (e0 + e1 + e2 + e3);
  const int c1 = tgt[b * 50 + (lane < 50 ? lane : 49)];
  const float pc = ((c1 == 1) ? e1 : (c1 == 2) ? e2 : e3) * inv;
  float* dst = G + ((size_t)b * 2008 + t) * 128 + lane * 2;
  *(float2*)dst = make_float2(e0 * inv, pc);
}

template <int RF> struct Row { float v[RF]; };

template <int RF>
__device__ __forceinline__ Row<RF> load_row(const float* p) {
  Row<RF> r;
  if constexpr (RF == 8) {
    const float4 a = *(const float4*)p;
    const float4 b = *(const float4*)(p + 4);
    r.v[0] = a.x; r.v[1] = a.y; r.v[2] = a.z; r.v[3] = a.w;
    r.v[4] = b.x; r.v[5] = b.y; r.v[6] = b.z; r.v[7] = b.w;
  } else {
    const float2 a = *(const float2*)p;
    r.v[0] = a.x; r.v[1] = a.y;
  }
  return r;
}

// One wave advances one chain; lane holds positions l=lane*R..lane*R+R-1.
// G rows: [64][RF] floats, 2008 rows. No DS ops in the T loop.
template <int R, int S, int RF>
__device__ __forceinline__ void chain_lin(
    const float* __restrict__ G, const int* __restrict__ tb,
    int len, int tl, float* __restrict__ out, double* sa) {
  constexpr int L = 2 * S + 1;
  constexpr int RSTRIDE = 64 * RF;  // floats per row
  const int lane = threadIdx.x;

  double skipm[R];
#pragma unroll
  for (int j = 0; j < R; ++j) {
    const int l = lane * R + j;
    bool sk = false;
    if (l & 1) {
      const int s = (l - 1) >> 1;
      if (s >= 1 && s < S) sk = (tb[s] != tb[s - 1]);
    }
    skipm[j] = sk ? 1.0 : 0.0;
  }

  const float* Gl = G + lane * RF;

  double alpha[R];
#pragma unroll
  for (int j = 0; j < R; ++j) alpha[j] = 0.0;
  {
    const Row<RF> r0 = load_row<RF>(Gl);  // t = 0
    if (lane == 0) {
      alpha[0] = (double)r0.v[0];
      alpha[1] = (double)r0.v[1];
    }
  }
  int K = 0;

  // 8-deep register-ring prefetch (static slot indices)
  Row<RF> buf[8];
#pragma unroll
  for (int u = 0; u < 8; ++u)
    buf[u] = load_row<RF>(Gl + (size_t)(1 + u) * RSTRIDE);

  const int tmain = 1 + ((len - 1) & ~7);
  for (int base = 1; base < tmain; base += 8) {
    // renorm every 16 steps: pin band max to ~2^500 (exp-field arithmetic,
    // no transcendentals, no DS). Target biased exponent 1523; clamp the
    // scale's exponent so it stays representable.
    if (((base - 1) & 15) == 0 && base > 1) {
      double mm = alpha[0];
#pragma unroll
      for (int j = 1; j < R; ++j) mm = fmax(mm, alpha[j]);
      const int ex = (__double2hiint(mm) >> 20) & 0x7ff;
      const int emax = wave_imax(ex);
      if (emax > 0) {
        int d = 1523 - emax;       // shift band max to biased exp ~1523
        if (d > 1023) d = 1023;    // keep 2^d representable
        const double sc = __hiloint2double((d + 1023) << 20, 0);
#pragma unroll
        for (int j = 0; j < R; ++j) alpha[j] *= sc;
        K += d;
      }
    }
#pragma unroll
    for (int u = 0; u < 8; ++u) {
      const int t = base + u;
      const Row<RF> f = buf[u];
      buf[u] = load_row<RF>(Gl + (size_t)(t + 8) * RSTRIDE);  // prefetch
      const double am1 = dpp_shr1_f64(alpha[R - 1]);
      const double am2 = dpp_shr1_f64(alpha[R - 2]);
      double na[R];
#pragma unroll
      for (int j = 0; j < R; ++j) {
        const double a0 = alpha[j];
        const double a1 = (j >= 1) ? alpha[j - 1] : am1;
        const double a2 = (j >= 2) ? alpha[j - 2] : ((j == 1) ? am1 : am2);
        double s = a0 + a1;
        s = fma(skipm[j], a2, s);
        na[j] = (double)f.v[j] * s;
      }
#pragma unroll
      for (int j = 0; j < R; ++j) alpha[j] = na[j];
    }
  }
  // tail (<8 steps, direct loads; <=23 steps since last renorm — safe)
  for (int t = tmain; t < len; ++t) {
    const Row<RF> f = load_row<RF>(Gl + (size_t)t * RSTRIDE);
    const double am1 = dpp_shr1_f64(alpha[R - 1]);
    const double am2 = dpp_shr1_f64(alpha[R - 2]);
    double na[R];
#pragma unroll
    for (int j = 0; j < R; ++j) {
      const double a0 = alpha[j];
      const double a1 = (j >= 1) ? alpha[j - 1] : am1;
      const double a2 = (j >= 2) ? alpha[j - 2] : ((j == 1) ? am1 : am2);
      double s = a0 + a1;
      s = fma(skipm[j], a2, s);
      na[j] = (double)f.v[j] * s;
    }
#pragma unroll
    for (int j = 0; j < R; ++j) alpha[j] = na[j];
  }

  // readout alpha[2tl-1] + alpha[2tl]
#pragma unroll
  for (int j = 0; j < R; ++j) {
    const int l = lane * R + j;
    if (l < L) sa[l] = alpha[j];
  }
  __syncthreads();
  if (lane == 0) {
    const double a = sa[2 * tl - 1] + sa[2 * tl];
    float loss = (float)((double)K * LN2D - log(a));
    if (!(loss < 1e29f)) loss = 0.f;  // zero_infinity
    atomicAdd(out, loss / ((float)tl * 32.0f));
  }
}

__global__ __launch_bounds__(64) void ctc_chains_fast_kernel(
    const float* __restrict__ G_ph, const float* __restrict__ G_err,
    const int* __restrict__ err_tgt, const int* __restrict__ ph_tgt,
    const int* __restrict__ err_il, const int* __restrict__ ph_il,
    const int* __restrict__ err_tl, const int* __restrict__ ph_tl,
    float* __restrict__ out) {
  __shared__ double sa[448];
  const int blk = blockIdx.x;
  if (blk < 32) {
    const int b = blk;
    int len = err_il[b]; if (len > 2000) len = 2000;
    chain_lin<2, 50, 2>(G_err + (size_t)b * 2008 * 128, err_tgt + b * 50,
                        len, err_tl[b], out, sa);
  } else {
    const int b = blk - 32;
    int len = ph_il[b]; if (len > 2000) len = 2000;
    chain_lin<7, 200, 8>(G_ph + (size_t)b * 2008 * 512, ph_tgt + b * 200,
                         len, ph_tl[b], out, sa);
  }
}

// ========================= fallback path (R2, proven) ======================

__global__ __launch_bounds__(256) void softmax4_kernel(
    const float* __restrict__ x, float* __restrict__ p, int nrows) {
  int r = blockIdx.x * blockDim.x + threadIdx.x;
  if (r >= nrows) return;
  float4 v = *reinterpret_cast<const float4*>(x + (size_t)r * 4);
  float z0 = v.x * LOG2E, z1 = v.y * LOG2E, z2 = v.z * LOG2E, z3 = v.w * LOG2E;
  float m = fmaxf(fmaxf(z0, z1), fmaxf(z2, z3));
  float e0 = fexp2(z0 - m), e1 = fexp2(z1 - m);
  float e2 = fexp2(z2 - m), e3 = fexp2(z3 - m);
  float inv = 1.0f / (e0 + e1 + e2 + e3);
  float4 o;
  o.x = e0 * inv; o.y = e1 * inv; o.z = e2 * inv; o.w = e3 * inv;
  *reinterpret_cast<float4*>(p + (size_t)r * 4) = o;
}

__global__ __launch_bounds__(256) void softmax64_kernel(
    const float* __restrict__ x, float* __restrict__ p, int nrows) {
  int row = blockIdx.x * 4 + (threadIdx.x >> 6);
  int lane = threadIdx.x & 63;
  if (row >= nrows) return;
  float z = x[(size_t)row * 64 + lane] * LOG2E;
  float m = z;
#pragma unroll
  for (int off = 32; off >= 1; off >>= 1) m = fmaxf(m, __shfl_xor(m, off, 64));
  float e = fexp2(z - m);
  float s = e;
#pragma unroll
  for (int off = 32; off >= 1; off >>= 1) s += __shfl_xor(s, off, 64);
  p[(size_t)row * 64 + lane] = e * (1.0f / s);
}

template <int C, int S, int R>
__device__ __forceinline__ void ctc_chain_lin_fb(
    const float* __restrict__ p_b, const int* __restrict__ tgt_b,
    int len, int tl, float* __restrict__ out, double* sa) {
  constexpr int L = 2 * S + 1;
  const int lane = threadIdx.x;
  int idx[R];
  double skipm[R];
#pragma unroll
  for (int j = 0; j < R; ++j) {
    const int l = lane * R + j;
    int cls = 0;
    bool sk = false;
    if (l & 1) {
      const int s = (l - 1) >> 1;
      const int sc = (s < S) ? s : (S - 1);
      cls = tgt_b[sc];
      if (s >= 1 && s < S) sk = (cls != tgt_b[s - 1]);
    }
    idx[j] = cls * 4;
    skipm[j] = sk ? 1.0 : 0.0;
  }
  double alpha[R];
#pragma unroll
  for (int j = 0; j < R; ++j) {
    const int l = lane * R + j;
    alpha[j] = (l <= 1) ? (double)p_b[idx[j] >> 2] : 0.0;
  }
  int K = 0;
  const int cl = lane & (C - 1);
  float rv = p_b[(size_t)((1 < len - 1) ? 1 : (len - 1)) * C + cl];
  float pf[R];
#pragma unroll
  for (int j = 0; j < R; ++j)
    pf[j] = __int_as_float(__builtin_amdgcn_ds_bpermute(idx[j], __float_as_int(rv)));
  rv = p_b[(size_t)((2 < len - 1) ? 2 : (len - 1)) * C + cl];
  for (int t = 1; t < len; ++t) {
    if ((t & 31) == 0) {
      double m = alpha[0];
#pragma unroll
      for (int j = 1; j < R; ++j) m = fmax(m, alpha[j]);
#pragma unroll
      for (int off = 1; off < 64; off <<= 1) m = fmax(m, __shfl_xor(m, off, 64));
      const long long bits = __double_as_longlong(m);
      const int e = (int)((bits >> 52) & 0x7FF);
      if (e > 0) {
        const double sc = __longlong_as_double((long long)(2046 - e) << 52);
#pragma unroll
        for (int j = 0; j < R; ++j) alpha[j] *= sc;
        K += 1023 - e;
      }
    }
    const int tn = (t + 2 < len) ? (t + 2) : (len - 1);
    const float rvn = p_b[(size_t)tn * C + cl];
    float pfn[R];
#pragma unroll
    for (int j = 0; j < R; ++j)
      pfn[j] = __int_as_float(__builtin_amdgcn_ds_bpermute(idx[j], __float_as_int(rv)));
    double am1 = __shfl_up(alpha[R - 1], 1, 64);
    double am2 = __shfl_up(alpha[R - 2], 1, 64);
    if (lane == 0) { am1 = 0.0; am2 = 0.0; }
    double na[R];
#pragma unroll
    for (int j = 0; j < R; ++j) {
      const double a0 = alpha[j];
      const double a1 = (j >= 1) ? alpha[j - 1] : am1;
      const double a2 = (j >= 2) ? alpha[j - 2] : ((j == 1) ? am1 : am2);
      double s = a0 + a1;
      s = fma(skipm[j], a2, s);
      na[j] = (double)pf[j] * s;
    }
#pragma unroll
    for (int j = 0; j < R; ++j) alpha[j] = na[j];
#pragma unroll
    for (int j = 0; j < R; ++j) pf[j] = pfn[j];
    rv = rvn;
  }
#pragma unroll
  for (int j = 0; j < R; ++j) {
    const int l = lane * R + j;
    if (l < L) sa[l] = alpha[j];
  }
  __syncthreads();
  if (lane == 0) {
    const double a = sa[2 * tl - 1] + sa[2 * tl];
    float loss = (float)((double)K * LN2D - log(a));
    if (!(loss < 1e29f)) loss = 0.0f;
    atomicAdd(out, loss / ((float)tl * 32.0f));
  }
}

__global__ __launch_bounds__(64) void ctc_chains_fb_kernel(
    const float* __restrict__ p_err, const float* __restrict__ p_ph,
    const int* __restrict__ err_tgt, const int* __restrict__ ph_tgt,
    const int* __restrict__ err_il, const int* __restrict__ ph_il,
    const int* __restrict__ err_tl, const int* __restrict__ ph_tl,
    float* __restrict__ out) {
  __shared__ double sa[512];
  const int T = 2000;
  const int blk = blockIdx.x;
  if (blk < 32) {
    const int b = blk;
    int len = err_il[b]; if (len > T) len = T;
    ctc_chain_lin_fb<4, 50, 2>(p_err + (size_t)b * T * 4, err_tgt + b * 50, len,
                               err_tl[b], out, sa);
  } else {
    const int b = blk - 32;
    int len = ph_il[b]; if (len > T) len = T;
    ctc_chain_lin_fb<64, 200, 7>(p_ph + (size_t)b * T * 64, ph_tgt + b * 200,
                                 len, ph_tl[b], out, sa);
  }
}

// ========================= launch ==========================================

extern "C" void kernel_launch(void* const* d_in, const int* in_sizes, int n_in,
                              void* d_out, int out_size, void* d_ws,
                              size_t ws_size, hipStream_t stream) {
  const float* err_logits = (const float*)d_in[0];
  const float* ph_logits  = (const float*)d_in[1];
  const int* err_tgt = (const int*)d_in[2];
  const int* ph_tgt  = (const int*)d_in[3];
  const int* err_il  = (const int*)d_in[4];
  const int* ph_il   = (const int*)d_in[5];
  const int* err_tl  = (const int*)d_in[6];
  const int* ph_tl   = (const int*)d_in[7];
  float* out = (float*)d_out;

  const size_t gph_floats = (size_t)32 * 2008 * 512;   // 131.6 MB
  const size_t gerr_floats = (size_t)32 * 2008 * 128;  //  32.9 MB
  const size_t need_fast = (gph_floats + gerr_floats) * sizeof(float);

  hipMemsetAsync(d_out, 0, sizeof(float), stream);

  if (ws_size >= need_fast) {
    float* G_ph = (float*)d_ws;
    float* G_err = G_ph + gph_floats;
    dim3 grid(500, 32);
    gather_ph_kernel<<<grid, 256, 0, stream>>>(ph_logits, ph_tgt, G_ph);
    gather_err_kernel<<<grid, 256, 0, stream>>>(err_logits, err_tgt, G_err);
    ctc_chains_fast_kernel<<<64, 64, 0, stream>>>(G_ph, G_err, err_tgt, ph_tgt,
                                                  err_il, ph_il, err_tl, ph_tl,
                                                  out);
  } else {
    const int B = 32, T = 2000;
    const int rows = B * T;
    float* p_err = (float*)d_ws;
    float* p_ph  = p_err + (size_t)rows * 4;
    softmax4_kernel<<<(rows + 255) / 256, 256, 0, stream>>>(err_logits, p_err, rows);
    softmax64_kernel<<<(rows + 3) / 4, 256, 0, stream>>>(ph_logits, p_ph, rows);
    ctc_chains_fb_kernel<<<64, 64, 0, stream>>>(p_err, p_ph, err_tgt, ph_tgt,
                                                err_il, ph_il, err_tl, ph_tl, out);
  }
}

// Round 5
// 260.355 us; speedup vs baseline: 3.0008x; 1.1791x over previous
//
#include <hip/hip_runtime.h>
#include <math.h>

// ---------------------------------------------------------------------------
// Dual CTC loss forward, linear-probability fp64 recursion, B/L split form.
//  error task:   B=32, T=2000, C=4,  S=50   (1 blank/label pair per lane)
//  phoneme task: B=32, T=2000, C=64, S=200  (4 pairs per lane)
// R5: B[s]=alpha[2s] (blank), L[s]=alpha[2s+1] (label).
//   B'[s] = pb * (B[s] + L[s-1])                      (2 f64 ops)
//   L'[s] = p_s * (B[s] + L[s] + skip_s * L[s-1])     (3 f64 ops)
//  - blank prob pb(t) is wave-uniform -> 1 broadcast dword load + 1 cvt
//  - G-label buffer: 4 floats/lane/row (phoneme) -> half the traffic of R4
//  - 8-deep register-ring prefetch; __launch_bounds__(64,1) so the ring
//    stays in VGPRs (R4's VGPR_Count=56 => ring was spilled)
//  - renorm every 16 steps pinned to ~2^500 (R4-proven)
// Falls back to the R2 (bpermute) proven path if ws_size too small.
// ---------------------------------------------------------------------------

static constexpr float  LOG2E = 1.4426950408889634f;
static constexpr double LN2D  = 0.6931471805599453;

#define DPP_WAVE_SHR1   0x138
#define DPP_ROW_SHR(n)  (0x110 | (n))
#define DPP_ROW_BCAST15 0x142
#define DPP_ROW_BCAST31 0x143

__device__ __forceinline__ float fexp2(float x) {
  return __builtin_amdgcn_exp2f(x);
}

// prev-lane value (lane i gets lane i-1; lane 0 gets 0.0) — pure VALU
__device__ __forceinline__ double dpp_shr1_f64(double x) {
  int lo = __double2loint(x), hi = __double2hiint(x);
  lo = __builtin_amdgcn_update_dpp(0, lo, DPP_WAVE_SHR1, 0xf, 0xf, true);
  hi = __builtin_amdgcn_update_dpp(0, hi, DPP_WAVE_SHR1, 0xf, 0xf, true);
  return __hiloint2double(hi, lo);
}

__device__ __forceinline__ int imax2(int a, int b) { return a > b ? a : b; }

__device__ __forceinline__ int wave_imax(int v) {
  v = imax2(v, __builtin_amdgcn_update_dpp(0, v, DPP_ROW_SHR(1), 0xf, 0xf, true));
  v = imax2(v, __builtin_amdgcn_update_dpp(0, v, DPP_ROW_SHR(2), 0xf, 0xf, true));
  v = imax2(v, __builtin_amdgcn_update_dpp(0, v, DPP_ROW_SHR(4), 0xf, 0xf, true));
  v = imax2(v, __builtin_amdgcn_update_dpp(0, v, DPP_ROW_SHR(8), 0xf, 0xf, true));
  v = imax2(v, __builtin_amdgcn_update_dpp(0, v, DPP_ROW_BCAST15, 0xf, 0xf, true));
  v = imax2(v, __builtin_amdgcn_update_dpp(0, v, DPP_ROW_BCAST31, 0xf, 0xf, true));
  return __builtin_amdgcn_readlane(v, 63);
}

// ========================= fast path =======================================

// phoneme gather: softmax over C=64 (one wave/row); store blank prob (lane 0)
// and 4 label probs per lane (s = 4*lane + k).
__global__ __launch_bounds__(256) void gather_ph_kernel(
    const float* __restrict__ logits, const int* __restrict__ tgt,
    float* __restrict__ Glab, float* __restrict__ Gb) {
  const int lane = threadIdx.x & 63;
  const int t = blockIdx.x * 4 + (threadIdx.x >> 6);
  const int b = blockIdx.y;
  const float z = logits[((size_t)b * 2000 + t) * 64 + lane] * LOG2E;
  float m = z;
#pragma unroll
  for (int off = 32; off >= 1; off >>= 1) m = fmaxf(m, __shfl_xor(m, off, 64));
  const float e = fexp2(z - m);
  float s = e;
#pragma unroll
  for (int off = 32; off >= 1; off >>= 1) s += __shfl_xor(s, off, 64);
  const float p = e * (1.0f / s);
  const int pi = __float_as_int(p);
  const int* tb = tgt + b * 200;
  float o[4];
#pragma unroll
  for (int k = 0; k < 4; ++k) {
    const int si = lane * 4 + k;
    const int cls = (si < 200) ? tb[si] : 0;
    const float v = __int_as_float(__builtin_amdgcn_ds_bpermute(cls << 2, pi));
    o[k] = (si < 200) ? v : 0.0f;  // dead label states stay exactly 0
  }
  *(float4*)(Glab + ((size_t)b * 2008 + t) * 256 + lane * 4) =
      make_float4(o[0], o[1], o[2], o[3]);
  if (lane == 0) Gb[(size_t)b * 2008 + t] = p;  // p[class 0] = blank
}

// error gather: per-row softmax over C=4 (redundant per lane, cheap)
__global__ __launch_bounds__(256) void gather_err_kernel(
    const float* __restrict__ logits, const int* __restrict__ tgt,
    float* __restrict__ Glab, float* __restrict__ Gb) {
  const int lane = threadIdx.x & 63;
  const int t = blockIdx.x * 4 + (threadIdx.x >> 6);
  const int b = blockIdx.y;
  const float4 v = *(const float4*)(logits + ((size_t)b * 2000 + t) * 4);
  const float z0 = v.x * LOG2E, z1 = v.y * LOG2E, z2 = v.z * LOG2E, z3 = v.w * LOG2E;
  const float m = fmaxf(fmaxf(z0, z1), fmaxf(z2, z3));
  const float e0 = fexp2(z0 - m), e1 = fexp2(z1 - m);
  const float e2 = fexp2(z2 - m), e3 = fexp2(z3 - m);
  const float inv = 1.0f / (e0 + e1 + e2 + e3);
  const int c1 = tgt[b * 50 + (lane < 50 ? lane : 49)];
  const float pc =
      (lane < 50) ? (((c1 == 1) ? e1 : (c1 == 2) ? e2 : e3) * inv) : 0.0f;
  Glab[((size_t)b * 2008 + t) * 64 + lane] = pc;
  if (lane == 0) Gb[(size_t)b * 2008 + t] = e0 * inv;
}

template <int P> struct RowP { float v[P]; };

template <int P>
__device__ __forceinline__ RowP<P> load_rowp(const float* p) {
  RowP<P> r;
  if constexpr (P == 4) {
    const float4 a = *(const float4*)p;
    r.v[0] = a.x; r.v[1] = a.y; r.v[2] = a.z; r.v[3] = a.w;
  } else {
    r.v[0] = *p;
  }
  return r;
}

// One wave advances one chain. Lane owns pairs s = lane*P .. lane*P+P-1:
// B[s]=alpha[2s], L[s]=alpha[2s+1]. No DS ops in the T loop.
template <int P, int S>
__device__ __forceinline__ void chain_bl(
    const float* __restrict__ Glab,  // [2008][64*P] label probs
    const float* __restrict__ Gb,    // [2008] blank probs
    const int* __restrict__ tb, int len, int tl,
    float* __restrict__ out, double* sa) {
  constexpr int LSTRIDE = 64 * P;
  const int lane = threadIdx.x;

  double skipm[P];
#pragma unroll
  for (int k = 0; k < P; ++k) {
    const int s = lane * P + k;
    skipm[k] = (s >= 1 && s < S && tb[s] != tb[s - 1]) ? 1.0 : 0.0;
  }

  double B[P], L[P];
#pragma unroll
  for (int k = 0; k < P; ++k) { B[k] = 0.0; L[k] = 0.0; }
  {
    const float pb0 = Gb[0];
    const float pl0 = Glab[0];  // lane 0's v[0] = p_{tgt[0]}(0)
    if (lane == 0) {
      B[0] = (double)pb0;
      L[0] = (double)pl0;
    }
  }
  int K = 0;

  const float* Gl = Glab + lane * P;
  // 8-deep register-ring prefetch (static slot indices)
  RowP<P> labbuf[8];
  float pbbuf[8];
#pragma unroll
  for (int u = 0; u < 8; ++u) {
    labbuf[u] = load_rowp<P>(Gl + (size_t)(1 + u) * LSTRIDE);
    pbbuf[u] = Gb[1 + u];
  }

  const int tmain = 1 + ((len - 1) & ~7);
  for (int base = 1; base < tmain; base += 8) {
    // renorm every 16 steps: pin band max to ~2^500 (R4-proven)
    if (((base - 1) & 15) == 0 && base > 1) {
      double mm = B[0];
#pragma unroll
      for (int k = 0; k < P; ++k) mm = fmax(fmax(mm, B[k]), L[k]);
      const int ex = (__double2hiint(mm) >> 20) & 0x7ff;
      const int emax = wave_imax(ex);
      if (emax > 0) {
        int d = 1523 - emax;
        if (d > 1023) d = 1023;
        const double sc = __hiloint2double((d + 1023) << 20, 0);
#pragma unroll
        for (int k = 0; k < P; ++k) { B[k] *= sc; L[k] *= sc; }
        K += d;
      }
    }
#pragma unroll
    for (int u = 0; u < 8; ++u) {
      const int t = base + u;
      const RowP<P> f = labbuf[u];
      const float pbf = pbbuf[u];
      labbuf[u] = load_rowp<P>(Gl + (size_t)(t + 8) * LSTRIDE);  // prefetch
      pbbuf[u] = Gb[t + 8];
      const double pbd = (double)pbf;
      const double Lm1 = dpp_shr1_f64(L[P - 1]);
      double nB[P], nL[P];
#pragma unroll
      for (int k = 0; k < P; ++k) {
        const double Lp = (k >= 1) ? L[k - 1] : Lm1;
        nB[k] = pbd * (B[k] + Lp);
        nL[k] = (double)f.v[k] * fma(skipm[k], Lp, B[k] + L[k]);
      }
#pragma unroll
      for (int k = 0; k < P; ++k) { B[k] = nB[k]; L[k] = nL[k]; }
    }
  }
  // tail (<8 steps, direct loads; <=23 steps since last renorm — safe)
  for (int t = tmain; t < len; ++t) {
    const RowP<P> f = load_rowp<P>(Gl + (size_t)t * LSTRIDE);
    const double pbd = (double)Gb[t];
    const double Lm1 = dpp_shr1_f64(L[P - 1]);
    double nB[P], nL[P];
#pragma unroll
    for (int k = 0; k < P; ++k) {
      const double Lp = (k >= 1) ? L[k - 1] : Lm1;
      nB[k] = pbd * (B[k] + Lp);
      nL[k] = (double)f.v[k] * fma(skipm[k], Lp, B[k] + L[k]);
    }
#pragma unroll
    for (int k = 0; k < P; ++k) { B[k] = nB[k]; L[k] = nL[k]; }
  }

  // readout: alpha[2tl-1] = L[tl-1], alpha[2tl] = B[tl]
  double* saB = sa;
  double* saL = sa + 64 * P;
#pragma unroll
  for (int k = 0; k < P; ++k) {
    saB[lane * P + k] = B[k];
    saL[lane * P + k] = L[k];
  }
  __syncthreads();
  if (lane == 0) {
    const double a = saL[tl - 1] + saB[tl];
    float loss = (float)((double)K * LN2D - log(a));
    if (!(loss < 1e29f)) loss = 0.f;  // zero_infinity
    atomicAdd(out, loss / ((float)tl * 32.0f));
  }
}

__global__ __launch_bounds__(64, 1) void ctc_chains_bl_kernel(
    const float* __restrict__ Glab_ph, const float* __restrict__ Gb_ph,
    const float* __restrict__ Glab_err, const float* __restrict__ Gb_err,
    const int* __restrict__ err_tgt, const int* __restrict__ ph_tgt,
    const int* __restrict__ err_il, const int* __restrict__ ph_il,
    const int* __restrict__ err_tl, const int* __restrict__ ph_tl,
    float* __restrict__ out) {
  __shared__ double sa[512];
  const int blk = blockIdx.x;
  if (blk < 32) {
    const int b = blk;
    int len = err_il[b]; if (len > 2000) len = 2000;
    chain_bl<1, 50>(Glab_err + (size_t)b * 2008 * 64, Gb_err + (size_t)b * 2008,
                    err_tgt + b * 50, len, err_tl[b], out, sa);
  } else {
    const int b = blk - 32;
    int len = ph_il[b]; if (len > 2000) len = 2000;
    chain_bl<4, 200>(Glab_ph + (size_t)b * 2008 * 256, Gb_ph + (size_t)b * 2008,
                     ph_tgt + b * 200, len, ph_tl[b], out, sa);
  }
}

// ========================= fallback path (R2, proven) ======================

__global__ __launch_bounds__(256) void softmax4_kernel(
    const float* __restrict__ x, float* __restrict__ p, int nrows) {
  int r = blockIdx.x * blockDim.x + threadIdx.x;
  if (r >= nrows) return;
  float4 v = *reinterpret_cast<const float4*>(x + (size_t)r * 4);
  float z0 = v.x * LOG2E, z1 = v.y * LOG2E, z2 = v.z * LOG2E, z3 = v.w * LOG2E;
  float m = fmaxf(fmaxf(z0, z1), fmaxf(z2, z3));
  float e0 = fexp2(z0 - m), e1 = fexp2(z1 - m);
  float e2 = fexp2(z2 - m), e3 = fexp2(z3 - m);
  float inv = 1.0f / (e0 + e1 + e2 + e3);
  float4 o;
  o.x = e0 * inv; o.y = e1 * inv; o.z = e2 * inv; o.w = e3 * inv;
  *reinterpret_cast<float4*>(p + (size_t)r * 4) = o;
}

__global__ __launch_bounds__(256) void softmax64_kernel(
    const float* __restrict__ x, float* __restrict__ p, int nrows) {
  int row = blockIdx.x * 4 + (threadIdx.x >> 6);
  int lane = threadIdx.x & 63;
  if (row >= nrows) return;
  float z = x[(size_t)row * 64 + lane] * LOG2E;
  float m = z;
#pragma unroll
  for (int off = 32; off >= 1; off >>= 1) m = fmaxf(m, __shfl_xor(m, off, 64));
  float e = fexp2(z - m);
  float s = e;
#pragma unroll
  for (int off = 32; off >= 1; off >>= 1) s += __shfl_xor(s, off, 64);
  p[(size_t)row * 64 + lane] = e * (1.0f / s);
}

template <int C, int S, int R>
__device__ __forceinline__ void ctc_chain_lin_fb(
    const float* __restrict__ p_b, const int* __restrict__ tgt_b,
    int len, int tl, float* __restrict__ out, double* sa) {
  constexpr int L = 2 * S + 1;
  const int lane = threadIdx.x;
  int idx[R];
  double skipm[R];
#pragma unroll
  for (int j = 0; j < R; ++j) {
    const int l = lane * R + j;
    int cls = 0;
    bool sk = false;
    if (l & 1) {
      const int s = (l - 1) >> 1;
      const int sc = (s < S) ? s : (S - 1);
      cls = tgt_b[sc];
      if (s >= 1 && s < S) sk = (cls != tgt_b[s - 1]);
    }
    idx[j] = cls * 4;
    skipm[j] = sk ? 1.0 : 0.0;
  }
  double alpha[R];
#pragma unroll
  for (int j = 0; j < R; ++j) {
    const int l = lane * R + j;
    alpha[j] = (l <= 1) ? (double)p_b[idx[j] >> 2] : 0.0;
  }
  int K = 0;
  const int cl = lane & (C - 1);
  float rv = p_b[(size_t)((1 < len - 1) ? 1 : (len - 1)) * C + cl];
  float pf[R];
#pragma unroll
  for (int j = 0; j < R; ++j)
    pf[j] = __int_as_float(__builtin_amdgcn_ds_bpermute(idx[j], __float_as_int(rv)));
  rv = p_b[(size_t)((2 < len - 1) ? 2 : (len - 1)) * C + cl];
  for (int t = 1; t < len; ++t) {
    if ((t & 31) == 0) {
      double m = alpha[0];
#pragma unroll
      for (int j = 1; j < R; ++j) m = fmax(m, alpha[j]);
#pragma unroll
      for (int off = 1; off < 64; off <<= 1) m = fmax(m, __shfl_xor(m, off, 64));
      const long long bits = __double_as_longlong(m);
      const int e = (int)((bits >> 52) & 0x7FF);
      if (e > 0) {
        const double sc = __longlong_as_double((long long)(2046 - e) << 52);
#pragma unroll
        for (int j = 0; j < R; ++j) alpha[j] *= sc;
        K += 1023 - e;
      }
    }
    const int tn = (t + 2 < len) ? (t + 2) : (len - 1);
    const float rvn = p_b[(size_t)tn * C + cl];
    float pfn[R];
#pragma unroll
    for (int j = 0; j < R; ++j)
      pfn[j] = __int_as_float(__builtin_amdgcn_ds_bpermute(idx[j], __float_as_int(rv)));
    double am1 = __shfl_up(alpha[R - 1], 1, 64);
    double am2 = __shfl_up(alpha[R - 2], 1, 64);
    if (lane == 0) { am1 = 0.0; am2 = 0.0; }
    double na[R];
#pragma unroll
    for (int j = 0; j < R; ++j) {
      const double a0 = alpha[j];
      const double a1 = (j >= 1) ? alpha[j - 1] : am1;
      const double a2 = (j >= 2) ? alpha[j - 2] : ((j == 1) ? am1 : am2);
      double s = a0 + a1;
      s = fma(skipm[j], a2, s);
      na[j] = (double)pf[j] * s;
    }
#pragma unroll
    for (int j = 0; j < R; ++j) alpha[j] = na[j];
#pragma unroll
    for (int j = 0; j < R; ++j) pf[j] = pfn[j];
    rv = rvn;
  }
#pragma unroll
  for (int j = 0; j < R; ++j) {
    const int l = lane * R + j;
    if (l < L) sa[l] = alpha[j];
  }
  __syncthreads();
  if (lane == 0) {
    const double a = sa[2 * tl - 1] + sa[2 * tl];
    float loss = (float)((double)K * LN2D - log(a));
    if (!(loss < 1e29f)) loss = 0.0f;
    atomicAdd(out, loss / ((float)tl * 32.0f));
  }
}

__global__ __launch_bounds__(64) void ctc_chains_fb_kernel(
    const float* __restrict__ p_err, const float* __restrict__ p_ph,
    const int* __restrict__ err_tgt, const int* __restrict__ ph_tgt,
    const int* __restrict__ err_il, const int* __restrict__ ph_il,
    const int* __restrict__ err_tl, const int* __restrict__ ph_tl,
    float* __restrict__ out) {
  __shared__ double sa[512];
  const int T = 2000;
  const int blk = blockIdx.x;
  if (blk < 32) {
    const int b = blk;
    int len = err_il[b]; if (len > T) len = T;
    ctc_chain_lin_fb<4, 50, 2>(p_err + (size_t)b * T * 4, err_tgt + b * 50, len,
                               err_tl[b], out, sa);
  } else {
    const int b = blk - 32;
    int len = ph_il[b]; if (len > T) len = T;
    ctc_chain_lin_fb<64, 200, 7>(p_ph + (size_t)b * T * 64, ph_tgt + b * 200,
                                 len, ph_tl[b], out, sa);
  }
}

// ========================= launch ==========================================

extern "C" void kernel_launch(void* const* d_in, const int* in_sizes, int n_in,
                              void* d_out, int out_size, void* d_ws,
                              size_t ws_size, hipStream_t stream) {
  const float* err_logits = (const float*)d_in[0];
  const float* ph_logits  = (const float*)d_in[1];
  const int* err_tgt = (const int*)d_in[2];
  const int* ph_tgt  = (const int*)d_in[3];
  const int* err_il  = (const int*)d_in[4];
  const int* ph_il   = (const int*)d_in[5];
  const int* err_tl  = (const int*)d_in[6];
  const int* ph_tl   = (const int*)d_in[7];
  float* out = (float*)d_out;

  const size_t glab_ph = (size_t)32 * 2008 * 256;  // 65.8 MB
  const size_t gb_ph   = (size_t)32 * 2008;
  const size_t glab_er = (size_t)32 * 2008 * 64;   // 16.4 MB
  const size_t gb_er   = (size_t)32 * 2008;
  const size_t need = (glab_ph + gb_ph + glab_er + gb_er) * sizeof(float);

  hipMemsetAsync(d_out, 0, sizeof(float), stream);

  if (ws_size >= need) {
    float* Glab_ph = (float*)d_ws;
    float* Gb_ph   = Glab_ph + glab_ph;
    float* Glab_er = Gb_ph + gb_ph;
    float* Gb_er   = Glab_er + glab_er;
    dim3 grid(500, 32);
    gather_ph_kernel<<<grid, 256, 0, stream>>>(ph_logits, ph_tgt, Glab_ph, Gb_ph);
    gather_err_kernel<<<grid, 256, 0, stream>>>(err_logits, err_tgt, Glab_er, Gb_er);
    ctc_chains_bl_kernel<<<64, 64, 0, stream>>>(Glab_ph, Gb_ph, Glab_er, Gb_er,
                                                err_tgt, ph_tgt, err_il, ph_il,
                                                err_tl, ph_tl, out);
  } else {
    const int B = 32, T = 2000;
    const int rows = B * T;
    float* p_err = (float*)d_ws;
    float* p_ph  = p_err + (size_t)rows * 4;
    softmax4_kernel<<<(rows + 255) / 256, 256, 0, stream>>>(err_logits, p_err, rows);
    softmax64_kernel<<<(rows + 3) / 4, 256, 0, stream>>>(ph_logits, p_ph, rows);
    ctc_chains_fb_kernel<<<64, 64, 0, stream>>>(p_err, p_ph, err_tgt, ph_tgt,
                                                err_il, ph_il, err_tl, ph_tl, out);
  }
}